// Round 10
// baseline (27969.214 us; speedup 1.0000x reference)
//
#include <hip/hip_runtime.h>

// ---------------------------------------------------------------------------
// MultiHeadAttention: out = softmax(mask( (xWq)(xWk)^T / sqrt(64) )) (xWv) Wo
// B=4 S=2048 D=1024 H=16 Dh=64. Inputs fp32, mask int32, OUTPUT FP32.
//
// R10: output dtype fix. R5/R6/R8/R9 wrote bf16 into an fp32 d_out ->
// harness read u16 pairs as fp32 -> right-scale decorrelated garbage with
// bit-identical absmax 0.3935 across implementations. ("bf16" in the error
// label is hardcoded in the harness f-string -- it never indicated output
// dtype.) Final GEMM now stores fp32.
//
// Pipeline: detect(guards) -> 4x wtrans (fp32 W^T) -> 3x GEMM (Q,K,V fp32)
//           -> naive fp32 attention -> GEMM (fp32 out -> d_out).
// Scratch: static __device__ arrays, device-side refs only.
// ---------------------------------------------------------------------------

typedef unsigned short u16;

__device__ float g_WT4[4][1024 * 1024];  // WqT, WkT, WvT, WoT (fp32)
__device__ float g_Q[8192 * 1024];
__device__ float g_K[8192 * 1024];
__device__ float g_V[8192 * 1024];
__device__ float g_O[8192 * 1024];
__device__ int g_is_bf16;    // guard: 1 = float inputs bf16, 0 = fp32
__device__ int g_mask_fmt;   // 0=int32 1=int64 2=float32 3=int8
__device__ float g_dev_beacon;

__device__ __forceinline__ float bf2f(u16 u) {
  union { unsigned int i; float f; } v;
  v.i = ((unsigned int)u) << 16;
  return v.f;
}

// ---------------------------------------------------------------------------
// float-dtype detector (guard): bf16 N(0,1) u16s ~100% in exponent band;
// fp32-as-u16 ~57%. Threshold 205/256.
// ---------------------------------------------------------------------------
__global__ void detect_kernel(const u16* __restrict__ q) {
  if (threadIdx.x == 0) {
    int cnt = 0;
    for (int i = 0; i < 256; ++i) {
      const u16 v = q[i];
      const int e = (v >> 7) & 0xFF;
      cnt += ((e >= 100 && e <= 135) || ((v & 0x7FFF) == 0)) ? 1 : 0;
    }
    g_is_bf16 = (cnt >= 205) ? 1 : 0;
  }
}

__device__ __forceinline__ float load_in(const void* p, size_t i) {
  return g_is_bf16 ? bf2f(((const u16*)p)[i]) : ((const float*)p)[i];
}

// ---------------------------------------------------------------------------
// mask-format detector (guard): classify first 16384 u32 words.
// ---------------------------------------------------------------------------
__global__ void mask_detect_kernel(const void* __restrict__ mask) {
  __shared__ int s_le1, s_oe, s_oo, s_f32, s_b01;
  const int t = threadIdx.x;
  if (t == 0) { s_le1 = 0; s_oe = 0; s_oo = 0; s_f32 = 0; s_b01 = 0; }
  __syncthreads();
  const unsigned int* w = (const unsigned int*)mask;
  int le1 = 0, oe = 0, oo = 0, f32 = 0, b01 = 0;
  for (int i = 0; i < 64; ++i) {
    const int idx = t * 64 + i;
    const unsigned int v = w[idx];
    le1 += (v <= 1u) ? 1 : 0;
    oe += (v == 1u && (idx & 1) == 0) ? 1 : 0;
    oo += (v == 1u && (idx & 1) == 1) ? 1 : 0;
    f32 += (v == 0x3F800000u) ? 1 : 0;
    const unsigned int b = v | (v >> 8) | (v >> 16) | (v >> 24);
    b01 += ((b & 0xFEu) == 0u) ? 1 : 0;
  }
  atomicAdd(&s_le1, le1); atomicAdd(&s_oe, oe); atomicAdd(&s_oo, oo);
  atomicAdd(&s_f32, f32); atomicAdd(&s_b01, b01);
  __syncthreads();
  if (t == 0) {
    const int W = 16384;
    int fmt = -1;
    if (s_le1 == W) fmt = (s_oo * 20 < s_oe) ? 1 : 0;  // int64 : int32
    else if (s_f32 > W / 8) fmt = 2;
    else if (s_b01 > (W * 9) / 10) fmt = 3;
    g_mask_fmt = (fmt < 0) ? 0 : fmt;
    g_dev_beacon = (fmt < 0) ? (350.f + (float)((s_le1 * 10) / W)) : 0.f;
  }
}

// ---------------------------------------------------------------------------
// 1024x1024 transpose -> fp32; out = g_WT4[wo]
// ---------------------------------------------------------------------------
__global__ void wtrans_kernel(const void* __restrict__ in, int wo) {
  __shared__ float tile[32][33];
  float* out = g_WT4[wo];
  const int tx = threadIdx.x, ty = threadIdx.y;
  const int n0 = blockIdx.x * 32, k0 = blockIdx.y * 32;
  tile[ty][tx] = load_in(in, (size_t)(k0 + ty) * 1024 + n0 + tx);
  __syncthreads();
  out[(size_t)(n0 + ty) * 1024 + k0 + tx] = tile[tx][ty];
}

// ---------------------------------------------------------------------------
// Pure-VALU fp32 GEMM: C[8192][1024] = A x g_WT4[bt]^T + bias.
// 64x64 tile, BK=16, 256 threads, 4x4 register blocking, +1-padded LDS.
// a_sel: 0 = Aptr (external input), 1 = g_O. c_sel: 0/1/2 = g_Q/g_K/g_V,
// 3 = Cptr fp32 (d_out).
// ---------------------------------------------------------------------------
__global__ __launch_bounds__(256) void gemm_f32_kernel(
    const void* __restrict__ Aptr, int a_sel, int bt,
    const void* __restrict__ bias, float* __restrict__ Cptr, int c_sel) {
  constexpr int K = 1024, N = 1024;
  __shared__ float Asf[64][17];
  __shared__ float Bsf[64][17];

  const float* Bt = g_WT4[bt];
  float* Cf = (c_sel == 0) ? g_Q : (c_sel == 1) ? g_K : (c_sel == 2) ? g_V : Cptr;

  const int t = threadIdx.x;
  const int tx = t & 15, ty = t >> 4;
  const int bm = blockIdx.x * 64, bn = blockIdx.y * 64;

  float acc[4][4] = {};

  for (int k0 = 0; k0 < K; k0 += 16) {
#pragma unroll
    for (int i = 0; i < 4; ++i) {
      const int idx = t + i * 256;  // 0..1023
      const int row = idx >> 4, kk = idx & 15;
      const size_t ga = (size_t)(bm + row) * K + k0 + kk;
      Asf[row][kk] = a_sel ? g_O[ga] : load_in(Aptr, ga);
      Bsf[row][kk] = Bt[(size_t)(bn + row) * K + k0 + kk];
    }
    __syncthreads();
#pragma unroll
    for (int kk = 0; kk < 16; ++kk) {
      float ar[4], br[4];
#pragma unroll
      for (int a = 0; a < 4; ++a) ar[a] = Asf[ty * 4 + a][kk];
#pragma unroll
      for (int b = 0; b < 4; ++b) br[b] = Bsf[tx * 4 + b][kk];
#pragma unroll
      for (int a = 0; a < 4; ++a)
#pragma unroll
        for (int b = 0; b < 4; ++b) acc[a][b] += ar[a] * br[b];
    }
    __syncthreads();
  }

#pragma unroll
  for (int b = 0; b < 4; ++b) {
    const int col = bn + tx * 4 + b;
    const float bv = g_is_bf16 ? bf2f(((const u16*)bias)[col])
                               : ((const float*)bias)[col];
#pragma unroll
    for (int a = 0; a < 4; ++a) {
      const int row = bm + ty * 4 + a;
      Cf[(size_t)row * N + col] = acc[a][b] + bv;  // fp32 store everywhere
    }
  }
}

// ---------------------------------------------------------------------------
// NAIVE fp32 attention, mask-format-aware. One wave per (b, h, q-row).
// ---------------------------------------------------------------------------
__global__ __launch_bounds__(64) void attn_naive_kernel(const void* __restrict__ mask) {
  constexpr int S = 2048, D = 1024;
  const int l = threadIdx.x;   // 0..63 = head dim
  const int qi = blockIdx.x;   // 0..2047
  const int h = blockIdx.y;    // 0..15
  const int b = blockIdx.z;    // 0..3
  const size_t bh = (size_t)b * S * D + (size_t)h * 64;
  const size_t mbase = (size_t)b * S * S + (size_t)qi * S;
  const int fmt = g_mask_fmt;

  const float q = g_Q[bh + (size_t)qi * D + l];

  float m = -1e30f, lsum = 0.f, o = 0.f;
  for (int j = 0; j < S; ++j) {
    float prod = q * g_K[bh + (size_t)j * D + l];
#pragma unroll
    for (int off = 1; off < 64; off <<= 1) prod += __shfl_xor(prod, off, 64);
    bool live;
    if (fmt == 1)      live = ((const long long*)mask)[mbase + j] != 0;
    else if (fmt == 2) live = ((const float*)mask)[mbase + j] != 0.0f;
    else if (fmt == 3) live = ((const signed char*)mask)[mbase + j] != 0;
    else               live = ((const int*)mask)[mbase + j] != 0;
    const float s = live ? prod * 0.125f : -1e9f;
    const float mn = fmaxf(m, s);
    const float alpha = __expf(m - mn);
    const float p = __expf(s - mn);
    lsum = lsum * alpha + p;
    o = o * alpha + p * g_V[bh + (size_t)j * D + l];
    m = mn;
  }
  g_O[bh + (size_t)qi * D + l] = o / lsum;
}

// ---------------------------------------------------------------------------
// beacon: overwrite d_out[0] (fp32) with a diagnostic code on anomaly
// ---------------------------------------------------------------------------
__global__ void beacon_kernel(float* out, float host_code) {
  if (threadIdx.x == 0) {
    float c = (host_code > 0.f) ? host_code : g_dev_beacon;
    if (c > 0.f) out[0] = c;
  }
}

// ---------------------------------------------------------------------------
extern "C" void kernel_launch(void* const* d_in, const int* in_sizes, int n_in,
                              void* d_out, int out_size, void* d_ws, size_t ws_size,
                              hipStream_t stream) {
  const void* query = d_in[0];
  const void* key   = d_in[1];
  const void* value = d_in[2];
  const void* mask  = d_in[3];
  const void* Wq = d_in[4];
  const void* bq = d_in[5];
  const void* Wk = d_in[6];
  const void* bk = d_in[7];
  const void* Wv = d_in[8];
  const void* bv = d_in[9];
  const void* Wo = d_in[10];
  const void* bo = d_in[11];

  // host-side layout verification -> beacon code
  float host_code = 0.f;
  if (n_in != 12) {
    host_code = 450.f + (float)(n_in < 49 ? n_in : 49);
  } else {
    static const int exp_sz[12] = {8388608, 8388608, 8388608, 16777216,
                                   1048576, 1024, 1048576, 1024,
                                   1048576, 1024, 1048576, 1024};
    bool ok = true;
    int idx_mask = 99;
    for (int i = 0; i < 12; ++i) {
      if (in_sizes[i] != exp_sz[i]) ok = false;
      if (in_sizes[i] == 16777216 && idx_mask == 99) idx_mask = i;
    }
    if (!ok) host_code = 300.f + (float)idx_mask;
    else if (out_size != 8388608) host_code = 480.f;
  }

  detect_kernel<<<1, 64, 0, stream>>>((const u16*)query);
  mask_detect_kernel<<<1, 256, 0, stream>>>(mask);

  dim3 tb(32, 32), tg(32, 32);
  wtrans_kernel<<<tg, tb, 0, stream>>>(Wq, 0);
  wtrans_kernel<<<tg, tb, 0, stream>>>(Wk, 1);
  wtrans_kernel<<<tg, tb, 0, stream>>>(Wv, 2);
  wtrans_kernel<<<tg, tb, 0, stream>>>(Wo, 3);

  dim3 gg(128, 16);  // 8192/64 x 1024/64
  gemm_f32_kernel<<<gg, 256, 0, stream>>>(query, 0, 0, bq, nullptr, 0);
  gemm_f32_kernel<<<gg, 256, 0, stream>>>(key,   0, 1, bk, nullptr, 1);
  gemm_f32_kernel<<<gg, 256, 0, stream>>>(value, 0, 2, bv, nullptr, 2);

  attn_naive_kernel<<<dim3(2048, 16, 4), 64, 0, stream>>>(mask);

  gemm_f32_kernel<<<gg, 256, 0, stream>>>(nullptr, 1, 3, bo, (float*)d_out, 3);

  beacon_kernel<<<1, 64, 0, stream>>>((float*)d_out, host_code);
}

// Round 11
// 2144.326 us; speedup vs baseline: 13.0434x; 13.0434x over previous
//
#include <hip/hip_runtime.h>

// ---------------------------------------------------------------------------
// MultiHeadAttention: out = softmax(mask( (xWq)(xWk)^T / sqrt(64) )) (xWv) Wo
// B=4 S=2048 D=1024 H=16 Dh=64. Inputs fp32, mask int32, output fp32
// (all confirmed on HW in R10: passed, absmax 9.77e-4).
//
// R11: replace naive attention (26.7ms, MfmaUtil=0, issue-bound) with MFMA
// flash attention. Q/K/V projections remain fp32-VALU GEMMs but store bf16
// (epilogue f2bf); attention does bf16 MFMA QK^T / PV with fp32 softmax and
// fp32 O; output projection remains fp32 (reads g_O fp32) -> d_out fp32.
// ---------------------------------------------------------------------------

typedef unsigned short u16;
typedef __attribute__((ext_vector_type(8))) short short8;
typedef __attribute__((ext_vector_type(8))) unsigned short u16x8;
typedef __attribute__((ext_vector_type(4))) float floatx4;

__device__ float g_WT4[4][1024 * 1024];  // WqT, WkT, WvT, WoT (fp32)
__device__ u16 g_Qh[8192 * 1024];        // bf16 Q projection
__device__ u16 g_Kh[8192 * 1024];        // bf16 K projection
__device__ u16 g_Vh[8192 * 1024];        // bf16 V projection
__device__ float g_O[8192 * 1024];       // fp32 attention output
__device__ int g_is_bf16;                // guard: input float dtype

__device__ __forceinline__ float bf2f(u16 u) {
  union { unsigned int i; float f; } v;
  v.i = ((unsigned int)u) << 16;
  return v.f;
}
__device__ __forceinline__ u16 f2bf(float f) {  // round-to-nearest-even
  union { float f; unsigned int i; } v;
  v.f = f;
  unsigned int r = v.i + 0x7fffu + ((v.i >> 16) & 1u);
  return (u16)(r >> 16);
}

// float-dtype guard (R6-validated): fp32 expected (g_is_bf16=0)
__global__ void detect_kernel(const u16* __restrict__ q) {
  if (threadIdx.x == 0) {
    int cnt = 0;
    for (int i = 0; i < 256; ++i) {
      const u16 v = q[i];
      const int e = (v >> 7) & 0xFF;
      cnt += ((e >= 100 && e <= 135) || ((v & 0x7FFF) == 0)) ? 1 : 0;
    }
    g_is_bf16 = (cnt >= 205) ? 1 : 0;
  }
}

__device__ __forceinline__ float load_in(const void* p, size_t i) {
  return g_is_bf16 ? bf2f(((const u16*)p)[i]) : ((const float*)p)[i];
}

// ---------------------------------------------------------------------------
// 1024x1024 transpose -> fp32; out = g_WT4[wo]
// ---------------------------------------------------------------------------
__global__ void wtrans_kernel(const void* __restrict__ in, int wo) {
  __shared__ float tile[32][33];
  float* out = g_WT4[wo];
  const int tx = threadIdx.x, ty = threadIdx.y;
  const int n0 = blockIdx.x * 32, k0 = blockIdx.y * 32;
  tile[ty][tx] = load_in(in, (size_t)(k0 + ty) * 1024 + n0 + tx);
  __syncthreads();
  out[(size_t)(n0 + ty) * 1024 + k0 + tx] = tile[tx][ty];
}

// ---------------------------------------------------------------------------
// Pure-VALU fp32 GEMM: C[8192][1024] = A x g_WT4[bt]^T + bias.
// 64x64 tile, BK=16, 256 threads, 4x4 register blocking, +1-padded LDS.
// a_sel: 0 = Aptr (external input), 1 = g_O (fp32).
// c_sel: 0/1/2 -> bf16 stores to g_Qh/g_Kh/g_Vh; 3 -> fp32 store to Cptr.
// ---------------------------------------------------------------------------
__global__ __launch_bounds__(256) void gemm_f32_kernel(
    const void* __restrict__ Aptr, int a_sel, int bt,
    const void* __restrict__ bias, float* __restrict__ Cptr, int c_sel) {
  constexpr int K = 1024, N = 1024;
  __shared__ float Asf[64][17];
  __shared__ float Bsf[64][17];

  const float* Bt = g_WT4[bt];
  u16* Ch = (c_sel == 0) ? g_Qh : (c_sel == 1) ? g_Kh : g_Vh;

  const int t = threadIdx.x;
  const int tx = t & 15, ty = t >> 4;
  const int bm = blockIdx.x * 64, bn = blockIdx.y * 64;

  float acc[4][4] = {};

  for (int k0 = 0; k0 < K; k0 += 16) {
#pragma unroll
    for (int i = 0; i < 4; ++i) {
      const int idx = t + i * 256;  // 0..1023
      const int row = idx >> 4, kk = idx & 15;
      const size_t ga = (size_t)(bm + row) * K + k0 + kk;
      Asf[row][kk] = a_sel ? g_O[ga] : load_in(Aptr, ga);
      Bsf[row][kk] = Bt[(size_t)(bn + row) * K + k0 + kk];
    }
    __syncthreads();
#pragma unroll
    for (int kk = 0; kk < 16; ++kk) {
      float ar[4], br[4];
#pragma unroll
      for (int a = 0; a < 4; ++a) ar[a] = Asf[ty * 4 + a][kk];
#pragma unroll
      for (int b = 0; b < 4; ++b) br[b] = Bsf[tx * 4 + b][kk];
#pragma unroll
      for (int a = 0; a < 4; ++a)
#pragma unroll
        for (int b = 0; b < 4; ++b) acc[a][b] += ar[a] * br[b];
    }
    __syncthreads();
  }

#pragma unroll
  for (int b = 0; b < 4; ++b) {
    const int col = bn + tx * 4 + b;
    const float bv = g_is_bf16 ? bf2f(((const u16*)bias)[col])
                               : ((const float*)bias)[col];
#pragma unroll
    for (int a = 0; a < 4; ++a) {
      const int row = bm + ty * 4 + a;
      const float v = acc[a][b] + bv;
      if (c_sel == 3)
        Cptr[(size_t)row * N + col] = v;
      else
        Ch[(size_t)row * N + col] = f2bf(v);
    }
  }
}

// ---------------------------------------------------------------------------
// MFMA flash attention: block = (64-q-tile, h, b), 256 threads (4 waves).
// Reads bf16 g_Qh/g_Kh/g_Vh + int32 mask; writes fp32 O to g_O.
// Wave w owns Q rows [w*16, w*16+16). Per 64-key tile:
//   S = Q K^T (mfma_f32_16x16x32_bf16; A: m=lane&15,k=quad*8+j;
//   C/D: col=lane&15,row=quad*4+reg) -> mask/scale -> online softmax
//   (per-quad shfl16, m/l replicated) -> P bf16 via LDS C->A round-trip
//   (barrier) -> O += P V (vT staged in LDS, transpose-on-store).
// LDS rows LD=72 u16 (144B, 16B-aligned ds_read_b128).
// ---------------------------------------------------------------------------
__global__ __launch_bounds__(256) void attn_mfma_kernel(const int* __restrict__ mask) {
  constexpr int S = 2048, D = 1024;
  constexpr int LD = 72;
  __shared__ __align__(16) u16 q_s[64 * LD];
  __shared__ __align__(16) u16 k_s[64 * LD];
  __shared__ __align__(16) u16 vt_s[64 * LD];  // vT[d][j]
  __shared__ __align__(16) u16 p_s[64 * LD];   // per-wave 16-row strips

  const int t = threadIdx.x;
  const int lane = t & 63;
  const int lanelo = lane & 15;
  const int quad = lane >> 4;
  const int wave = t >> 6;

  const int q0 = blockIdx.x * 64;
  const int h = blockIdx.y;
  const int b = blockIdx.z;
  const size_t bh = (size_t)b * S * D + (size_t)h * 64;

  // stage Q tile [64 x 64]: row j = t&63, col chunks cc = (wave+4i)*8
  {
    const int j = t & 63;
#pragma unroll
    for (int i = 0; i < 2; ++i) {
      const int cc = (wave + i * 4) * 8;
      *(u16x8*)&q_s[j * LD + cc] =
          *(const u16x8*)(g_Qh + bh + (size_t)(q0 + j) * D + cc);
    }
  }

  floatx4 o_acc[4];
#pragma unroll
  for (int ni = 0; ni < 4; ++ni) o_acc[ni] = (floatx4)(0.f);
  float m_r[4] = {-1e30f, -1e30f, -1e30f, -1e30f};
  float l_r[4] = {0.f, 0.f, 0.f, 0.f};

  for (int kt = 0; kt < S / 64; ++kt) {
    const int j0 = kt * 64;
    __syncthreads();  // prev-iter LDS reads done (and q_s visible on kt=0)
    {
      const int j = t & 63;
#pragma unroll
      for (int i = 0; i < 2; ++i) {
        const int cc = (wave + i * 4) * 8;
        *(u16x8*)&k_s[j * LD + cc] =
            *(const u16x8*)(g_Kh + bh + (size_t)(j0 + j) * D + cc);
        const u16x8 vv = *(const u16x8*)(g_Vh + bh + (size_t)(j0 + j) * D + cc);
#pragma unroll
        for (int u = 0; u < 8; ++u) vt_s[(cc + u) * LD + j] = vv[u];  // transpose
      }
    }
    __syncthreads();

    // scores [16q x 64j] per wave
    floatx4 sacc[4];
#pragma unroll
    for (int ni = 0; ni < 4; ++ni) sacc[ni] = (floatx4)(0.f);
#pragma unroll
    for (int kk = 0; kk < 2; ++kk) {
      const short8 a =
          *(const short8*)&q_s[(wave * 16 + lanelo) * LD + kk * 32 + quad * 8];
#pragma unroll
      for (int ni = 0; ni < 4; ++ni) {
        const short8 bb =
            *(const short8*)&k_s[(ni * 16 + lanelo) * LD + kk * 32 + quad * 8];
        sacc[ni] = __builtin_amdgcn_mfma_f32_16x16x32_bf16(a, bb, sacc[ni], 0, 0, 0);
      }
    }

    // mask + scale; element (ni,r): row=quad*4+r, col=ni*16+lanelo
    float sc[4][4];
    const int gi0 = q0 + wave * 16 + quad * 4;
    const int* mb = mask + (size_t)b * S * S + j0 + lanelo;
#pragma unroll
    for (int r = 0; r < 4; ++r) {
      const int* mp = mb + (size_t)(gi0 + r) * S;
#pragma unroll
      for (int ni = 0; ni < 4; ++ni)
        sc[ni][r] = (mp[ni * 16] != 0) ? sacc[ni][r] * 0.125f : -1e9f;
    }

    // online softmax per row r; reduce across the quad's 16 lanes
#pragma unroll
    for (int r = 0; r < 4; ++r) {
      float mloc = fmaxf(fmaxf(sc[0][r], sc[1][r]), fmaxf(sc[2][r], sc[3][r]));
#pragma unroll
      for (int off = 1; off < 16; off <<= 1)
        mloc = fmaxf(mloc, __shfl_xor(mloc, off, 16));
      const float m_new = fmaxf(m_r[r], mloc);
      const float alpha = __expf(m_r[r] - m_new);
      m_r[r] = m_new;
      float ps = 0.f;
#pragma unroll
      for (int ni = 0; ni < 4; ++ni) {
        const float p = __expf(sc[ni][r] - m_new);
        ps += p;
        p_s[(wave * 16 + quad * 4 + r) * LD + ni * 16 + lanelo] = f2bf(p);
      }
#pragma unroll
      for (int off = 1; off < 16; off <<= 1) ps += __shfl_xor(ps, off, 16);
      l_r[r] = l_r[r] * alpha + ps;
#pragma unroll
      for (int ni = 0; ni < 4; ++ni) o_acc[ni][r] *= alpha;
    }

    __syncthreads();  // order cross-lane p_s writes before A-layout reads

    // O += P V
#pragma unroll
    for (int kk = 0; kk < 2; ++kk) {
      const short8 a =
          *(const short8*)&p_s[(wave * 16 + lanelo) * LD + kk * 32 + quad * 8];
#pragma unroll
      for (int ni = 0; ni < 4; ++ni) {
        const short8 bb =
            *(const short8*)&vt_s[(ni * 16 + lanelo) * LD + kk * 32 + quad * 8];
        o_acc[ni] = __builtin_amdgcn_mfma_f32_16x16x32_bf16(a, bb, o_acc[ni], 0, 0, 0);
      }
    }
  }

  // epilogue: divide by l, store fp32 O
#pragma unroll
  for (int ni = 0; ni < 4; ++ni) {
#pragma unroll
    for (int r = 0; r < 4; ++r) {
      const int row = q0 + wave * 16 + quad * 4 + r;
      g_O[bh + (size_t)row * D + ni * 16 + lanelo] = o_acc[ni][r] / l_r[r];
    }
  }
}

// ---------------------------------------------------------------------------
extern "C" void kernel_launch(void* const* d_in, const int* in_sizes, int n_in,
                              void* d_out, int out_size, void* d_ws, size_t ws_size,
                              hipStream_t stream) {
  const void* query = d_in[0];
  const void* key   = d_in[1];
  const void* value = d_in[2];
  const int* mask   = (const int*)d_in[3];
  const void* Wq = d_in[4];
  const void* bq = d_in[5];
  const void* Wk = d_in[6];
  const void* bk = d_in[7];
  const void* Wv = d_in[8];
  const void* bv = d_in[9];
  const void* Wo = d_in[10];
  const void* bo = d_in[11];

  detect_kernel<<<1, 64, 0, stream>>>((const u16*)query);

  dim3 tb(32, 32), tg(32, 32);
  wtrans_kernel<<<tg, tb, 0, stream>>>(Wq, 0);
  wtrans_kernel<<<tg, tb, 0, stream>>>(Wk, 1);
  wtrans_kernel<<<tg, tb, 0, stream>>>(Wv, 2);
  wtrans_kernel<<<tg, tb, 0, stream>>>(Wo, 3);

  dim3 gg(128, 16);  // 8192/64 x 1024/64
  gemm_f32_kernel<<<gg, 256, 0, stream>>>(query, 0, 0, bq, nullptr, 0);
  gemm_f32_kernel<<<gg, 256, 0, stream>>>(key,   0, 1, bk, nullptr, 1);
  gemm_f32_kernel<<<gg, 256, 0, stream>>>(value, 0, 2, bv, nullptr, 2);

  attn_mfma_kernel<<<dim3(32, 16, 4), 256, 0, stream>>>(mask);

  gemm_f32_kernel<<<gg, 256, 0, stream>>>(nullptr, 1, 3, bo, (float*)d_out, 3);
}